// Round 1
// baseline (147.208 us; speedup 1.0000x reference)
//
#include <hip/hip_runtime.h>

// VQ-VAE forward + EMA update, MI355X.
// Sizes fixed by the reference: B=64, C=D=8, H=W=64, K=512.
constexpr int Kc   = 512;
constexpr int Dc   = 8;
constexpr int HWc  = 4096;            // 64*64
constexpr int CHWc = Dc * HWc;        // 32768
constexpr int Mc   = 64 * HWc;        // 262144 vectors
constexpr int TOTALc = Mc * Dc;       // 2097152 elements of z / z_q

// d_ws float layout:
//   [0..511]     counts accumulator
//   [512..4607]  sums[k][c] accumulator
//   [4608]       loss sum accumulator
//   [4609..5120] e_sq[k]
__global__ __launch_bounds__(512) void vq_prep(const float* __restrict__ cb,
                                               float* __restrict__ ws) {
    const int k = threadIdx.x;  // 512 threads, 1 block
    float s = 0.f;
#pragma unroll
    for (int c = 0; c < Dc; ++c) {
        const float e = cb[k * Dc + c];
        s = fmaf(e, e, s);
    }
    ws[4609 + k] = s;
    ws[k] = 0.f;
#pragma unroll
    for (int c = 0; c < Dc; ++c) ws[512 + k * Dc + c] = 0.f;
    if (k == 0) ws[4608] = 0.f;
}

__global__ __launch_bounds__(256) void vq_main(const float* __restrict__ z,
                                               const float* __restrict__ cb,
                                               const float* __restrict__ esq,
                                               float* __restrict__ acc,   // ws base
                                               float* __restrict__ zq) {
    __shared__ float s_counts[Kc];
    __shared__ float s_sums[Kc * Dc];
    __shared__ float s_loss;

    const int t = threadIdx.x;
    for (int i = t; i < Kc; i += 256) s_counts[i] = 0.f;
    for (int i = t; i < Kc * Dc; i += 256) s_sums[i] = 0.f;
    if (t == 0) s_loss = 0.f;
    __syncthreads();

    // Each block: 512 consecutive vectors (aligned, so one batch index b).
    const int m0 = blockIdx.x * 512 + t;
    const int n0 = m0 & (HWc - 1);
    const int n1 = n0 + 256;              // still < HWc (512-aligned chunk)
    const int b  = m0 >> 12;
    const float* zb = z + b * CHWc;

    float z0[Dc], z1[Dc], zz0[Dc], zz1[Dc];
#pragma unroll
    for (int c = 0; c < Dc; ++c) {
        z0[c] = zb[c * HWc + n0];         // coalesced across lanes
        z1[c] = zb[c * HWc + n1];
        zz0[c] = -2.0f * z0[c];
        zz1[c] = -2.0f * z1[c];
    }

    // argmin_k ( e_sq[k] - 2 * dot(z, e_k) )  -- monotone-equivalent to ref.
    float mn0 = 3.4e38f, mn1 = 3.4e38f;
    int   i0 = 0, i1 = 0;
#pragma unroll 4
    for (int k = 0; k < Kc; ++k) {
        float a0 = esq[k];                // uniform -> s_load
        float a1 = a0;
#pragma unroll
        for (int c = 0; c < Dc; ++c) {
            const float e = cb[k * Dc + c];   // uniform -> s_load
            a0 = fmaf(zz0[c], e, a0);
            a1 = fmaf(zz1[c], e, a1);
        }
        const bool c0 = a0 < mn0;   // strict <: first index wins ties (ref rule)
        mn0 = c0 ? a0 : mn0;
        i0  = c0 ? k  : i0;
        const bool c1 = a1 < mn1;
        mn1 = c1 ? a1 : mn1;
        i1  = c1 ? k  : i1;
    }

    // Gather old-codebook rows (16 KB table, L1-hot; 32B/lane vector loads).
    const float4* cb4 = (const float4*)cb;
    const float4 qa0 = cb4[i0 * 2], qb0 = cb4[i0 * 2 + 1];
    const float4 qa1 = cb4[i1 * 2], qb1 = cb4[i1 * 2 + 1];
    const float q0[Dc] = {qa0.x, qa0.y, qa0.z, qa0.w, qb0.x, qb0.y, qb0.z, qb0.w};
    const float q1[Dc] = {qa1.x, qa1.y, qa1.z, qa1.w, qb1.x, qb1.y, qb1.z, qb1.w};

    float* zqb = zq + b * CHWc;
    float lsum = 0.f;
#pragma unroll
    for (int c = 0; c < Dc; ++c) {
        zqb[c * HWc + n0] = q0[c];        // coalesced stores
        zqb[c * HWc + n1] = q1[c];
        const float d0 = q0[c] - z0[c];
        const float d1 = q1[c] - z1[c];
        lsum = fmaf(d0, d0, lsum);
        lsum = fmaf(d1, d1, lsum);
    }

    // Per-block LDS histogram (ds_add_f32).
    unsafeAtomicAdd(&s_counts[i0], 1.0f);
    unsafeAtomicAdd(&s_counts[i1], 1.0f);
#pragma unroll
    for (int c = 0; c < Dc; ++c) {
        unsafeAtomicAdd(&s_sums[i0 * Dc + c], z0[c]);
        unsafeAtomicAdd(&s_sums[i1 * Dc + c], z1[c]);
    }
    unsafeAtomicAdd(&s_loss, lsum);
    __syncthreads();

    // Flush non-zero bins to global accumulators.
    for (int i = t; i < Kc; i += 256) {
        const float v = s_counts[i];
        if (v != 0.f) unsafeAtomicAdd(&acc[i], v);
    }
    for (int i = t; i < Kc * Dc; i += 256) {
        const float v = s_sums[i];
        if (v != 0.f) unsafeAtomicAdd(&acc[512 + i], v);
    }
    if (t == 0) unsafeAtomicAdd(&acc[4608], s_loss);
}

__global__ __launch_bounds__(512) void vq_final(const float* __restrict__ ws,
                                                const float* __restrict__ ema_cs,
                                                const float* __restrict__ ema_w,
                                                float* __restrict__ out) {
    constexpr float DEC  = 0.99f;
    constexpr float OMD  = (float)(1.0 - 0.99);      // matches jnp f32 cast
    constexpr float EPSf = 1e-5f;
    constexpr float KEPS = (float)(512 * 1e-5);      // 0.00512
    __shared__ float red[512];

    const int k = threadIdx.x;   // 512 threads, 1 block
    const float cnt = ws[k];
    const float ncs = ema_cs[k] * DEC + cnt * OMD;
    red[k] = ncs;
    __syncthreads();
    for (int s = 256; s > 0; s >>= 1) {
        if (k < s) red[k] += red[k + s];
        __syncthreads();
    }
    const float n  = red[0];
    const float cs = (ncs + EPSf) / (n + KEPS) * n;

    float* out_loss = out + TOTALc;          // [1]
    float* out_cb   = out + TOTALc + 1;      // [K*D]
    float* out_cs   = out_cb + Kc * Dc;      // [K]
    float* out_nw   = out_cs + Kc;           // [K*D]

    out_cs[k] = cs;
#pragma unroll
    for (int c = 0; c < Dc; ++c) {
        const float nw = ema_w[k * Dc + c] * DEC + ws[512 + k * Dc + c] * OMD;
        out_nw[k * Dc + c] = nw;
        out_cb[k * Dc + c] = nw / cs;
    }
    if (k == 0) out_loss[0] = ws[4608] * (1.0f / 2097152.0f);  // /2^21 exact
}

extern "C" void kernel_launch(void* const* d_in, const int* in_sizes, int n_in,
                              void* d_out, int out_size, void* d_ws, size_t ws_size,
                              hipStream_t stream) {
    const float* z      = (const float*)d_in[0];
    const float* cb     = (const float*)d_in[1];
    const float* ema_cs = (const float*)d_in[2];
    const float* ema_w  = (const float*)d_in[3];
    float* out = (float*)d_out;
    float* ws  = (float*)d_ws;

    vq_prep<<<1, 512, 0, stream>>>(cb, ws);
    vq_main<<<Mc / 512, 256, 0, stream>>>(z, cb, ws + 4609, ws, out);
    vq_final<<<1, 512, 0, stream>>>(ws, ema_cs, ema_w, out);
}

// Round 2
// 139.227 us; speedup vs baseline: 1.0573x; 1.0573x over previous
//
#include <hip/hip_runtime.h>

// VQ-VAE forward + EMA update, MI355X.
// Sizes fixed by the reference: B=64, C=D=8, H=W=64, K=512.
constexpr int Kc   = 512;
constexpr int Dc   = 8;
constexpr int HWc  = 4096;            // 64*64
constexpr int CHWc = Dc * HWc;        // 32768
constexpr int Mc   = 64 * HWc;        // 262144 vectors
constexpr int TOTALc = Mc * Dc;       // 2097152 elements of z / z_q

// 8 replica accumulators (one per XCD via blockIdx&7) to cut atomic contention.
constexpr int REP      = 8;
constexpr int RSTRIDE  = 4616;        // 512 counts + 4096 sums + 1 loss + 7 pad
constexpr int ACC_FLOATS = REP * RSTRIDE;   // 36928 floats (~148 KB)
// d_ws float layout:
//   [0 .. ACC_FLOATS)            replica accumulators (counts | sums | loss | pad) x8
//   [ACC_FLOATS .. +512)         e_sq[k]

__global__ __launch_bounds__(256) void vq_prep(const float* __restrict__ cb,
                                               float* __restrict__ ws) {
    const int tid = blockIdx.x * 256 + threadIdx.x;
    float4* w4 = (float4*)ws;
    for (int i = tid; i < ACC_FLOATS / 4; i += gridDim.x * 256)
        w4[i] = float4{0.f, 0.f, 0.f, 0.f};
    if (blockIdx.x == 0) {
        for (int k = threadIdx.x; k < Kc; k += 256) {
            float s = 0.f;
#pragma unroll
            for (int c = 0; c < Dc; ++c) {
                const float e = cb[k * Dc + c];
                s = fmaf(e, e, s);
            }
            ws[ACC_FLOATS + k] = s;
        }
    }
}

__global__ __launch_bounds__(256) void vq_main(const float* __restrict__ z,
                                               const float* __restrict__ cb,
                                               const float* __restrict__ esq,
                                               float* __restrict__ ws,
                                               float* __restrict__ zq) {
    __shared__ float s_counts[Kc];
    __shared__ float s_sums[Kc * Dc];
    __shared__ float s_loss;

    const int t = threadIdx.x;
    for (int i = t; i < Kc; i += 256) s_counts[i] = 0.f;
    for (int i = t; i < Kc * Dc; i += 256) s_sums[i] = 0.f;
    if (t == 0) s_loss = 0.f;
    __syncthreads();

    // 1 vector per thread: 1024 blocks x 256 threads = 262144 vectors.
    // 4 blocks/CU -> 16 waves/CU (the round-1 kernel was grid-limited to 8).
    const int m = blockIdx.x * 256 + t;
    const int n = m & (HWc - 1);
    const int b = m >> 12;
    const float* zb = z + b * CHWc + n;

    float zv[Dc], zz[Dc];
#pragma unroll
    for (int c = 0; c < Dc; ++c) {
        zv[c] = zb[c * HWc];              // coalesced across lanes
        zz[c] = -2.0f * zv[c];
    }

    // argmin_k ( e_sq[k] - 2 * dot(z, e_k) )  -- monotone-equivalent to ref.
    float mn = 3.4e38f;
    int   im = 0;
#pragma unroll 4
    for (int k = 0; k < Kc; ++k) {
        float a = esq[k];                 // uniform -> s_load
#pragma unroll
        for (int c = 0; c < Dc; ++c) {
            const float e = cb[k * Dc + c];   // uniform -> s_load
            a = fmaf(zz[c], e, a);
        }
        const bool cm = a < mn;  // strict <: first index wins ties (ref rule)
        mn = cm ? a : mn;
        im = cm ? k : im;
    }

    // Gather old-codebook row (16 KB table, L1-hot; 32B/lane vector loads).
    const float4* cb4 = (const float4*)cb;
    const float4 qa = cb4[im * 2], qb = cb4[im * 2 + 1];
    const float q[Dc] = {qa.x, qa.y, qa.z, qa.w, qb.x, qb.y, qb.z, qb.w};

    float* zqb = zq + b * CHWc + n;
    float lsum = 0.f;
#pragma unroll
    for (int c = 0; c < Dc; ++c) {
        zqb[c * HWc] = q[c];              // coalesced stores
        const float d = q[c] - zv[c];
        lsum = fmaf(d, d, lsum);
    }

    // Per-block LDS histogram (ds_add_f32).
    unsafeAtomicAdd(&s_counts[im], 1.0f);
#pragma unroll
    for (int c = 0; c < Dc; ++c)
        unsafeAtomicAdd(&s_sums[im * Dc + c], zv[c]);
    unsafeAtomicAdd(&s_loss, lsum);
    __syncthreads();

    // Flush non-zero bins to this block's replica accumulator.
    float* acc = ws + (blockIdx.x & (REP - 1)) * RSTRIDE;
    for (int i = t; i < Kc; i += 256) {
        const float v = s_counts[i];
        if (v != 0.f) unsafeAtomicAdd(&acc[i], v);
    }
    for (int i = t; i < Kc * Dc; i += 256) {
        const float v = s_sums[i];
        if (v != 0.f) unsafeAtomicAdd(&acc[512 + i], v);
    }
    if (t == 0) unsafeAtomicAdd(&acc[4608], s_loss);
}

__global__ __launch_bounds__(512) void vq_final(const float* __restrict__ ws,
                                                const float* __restrict__ ema_cs,
                                                const float* __restrict__ ema_w,
                                                float* __restrict__ out) {
    constexpr float DEC  = 0.99f;
    constexpr float OMD  = (float)(1.0 - 0.99);      // matches jnp f32 cast
    constexpr float EPSf = 1e-5f;
    constexpr float KEPS = (float)(512 * 1e-5);      // 0.00512
    __shared__ float red[512];

    const int k = threadIdx.x;   // 512 threads, 1 block
    float cnt = 0.f;
#pragma unroll
    for (int r = 0; r < REP; ++r) cnt += ws[r * RSTRIDE + k];
    const float ncs = ema_cs[k] * DEC + cnt * OMD;
    red[k] = ncs;
    __syncthreads();
    for (int s = 256; s > 0; s >>= 1) {
        if (k < s) red[k] += red[k + s];
        __syncthreads();
    }
    const float n  = red[0];
    const float cs = (ncs + EPSf) / (n + KEPS) * n;

    float* out_loss = out + TOTALc;          // [1]
    float* out_cb   = out + TOTALc + 1;      // [K*D]
    float* out_cs   = out_cb + Kc * Dc;      // [K]
    float* out_nw   = out_cs + Kc;           // [K*D]

    out_cs[k] = cs;
#pragma unroll
    for (int c = 0; c < Dc; ++c) {
        float sm = 0.f;
#pragma unroll
        for (int r = 0; r < REP; ++r) sm += ws[r * RSTRIDE + 512 + k * Dc + c];
        const float nw = ema_w[k * Dc + c] * DEC + sm * OMD;
        out_nw[k * Dc + c] = nw;
        out_cb[k * Dc + c] = nw / cs;
    }
    if (k == 0) {
        float ls = 0.f;
#pragma unroll
        for (int r = 0; r < REP; ++r) ls += ws[r * RSTRIDE + 4608];
        out_loss[0] = ls * (1.0f / 2097152.0f);  // /2^21 exact
    }
}

extern "C" void kernel_launch(void* const* d_in, const int* in_sizes, int n_in,
                              void* d_out, int out_size, void* d_ws, size_t ws_size,
                              hipStream_t stream) {
    const float* z      = (const float*)d_in[0];
    const float* cb     = (const float*)d_in[1];
    const float* ema_cs = (const float*)d_in[2];
    const float* ema_w  = (const float*)d_in[3];
    float* out = (float*)d_out;
    float* ws  = (float*)d_ws;

    vq_prep<<<32, 256, 0, stream>>>(cb, ws);
    vq_main<<<Mc / 256, 256, 0, stream>>>(z, cb, ws + ACC_FLOATS, ws, out);
    vq_final<<<1, 512, 0, stream>>>(ws, ema_cs, ema_w, out);
}

// Round 3
// 129.256 us; speedup vs baseline: 1.1389x; 1.0771x over previous
//
#include <hip/hip_runtime.h>

// VQ-VAE forward + EMA update, MI355X.
// Sizes fixed by the reference: B=64, C=D=8, H=W=64, K=512.
constexpr int Kc   = 512;
constexpr int Dc   = 8;
constexpr int HWc  = 4096;            // 64*64
constexpr int CHWc = Dc * HWc;        // 32768
constexpr int Mc   = 64 * HWc;        // 262144 vectors
constexpr int TOTALc = Mc * Dc;       // 2097152 elements of z / z_q

// 8 replica accumulators (one per XCD via blockIdx&7) to cut atomic contention.
constexpr int REP      = 8;
constexpr int RSTRIDE  = 4616;        // 512 counts + 4096 sums + 1 loss + 7 pad
constexpr int ACC_FLOATS = REP * RSTRIDE;   // 36928 floats (~148 KB)
// d_ws float layout:
//   [0 .. ACC_FLOATS)            replica accumulators (counts | sums | loss | pad) x8
//   [ACC_FLOATS .. +512)         e_sq[k]

__global__ __launch_bounds__(256) void vq_prep(const float* __restrict__ cb,
                                               float* __restrict__ ws) {
    const int tid = blockIdx.x * 256 + threadIdx.x;
    float4* w4 = (float4*)ws;
    for (int i = tid; i < ACC_FLOATS / 4; i += gridDim.x * 256)
        w4[i] = float4{0.f, 0.f, 0.f, 0.f};
    if (blockIdx.x == 0) {
        for (int k = threadIdx.x; k < Kc; k += 256) {
            float s = 0.f;
#pragma unroll
            for (int c = 0; c < Dc; ++c) {
                const float e = cb[k * Dc + c];
                s = fmaf(e, e, s);
            }
            ws[ACC_FLOATS + k] = s;
        }
    }
}

// 1024 blocks x 512 threads. Each block owns 256 vectors; waves 0-3 scan
// k in [0,256), waves 4-7 scan k in [256,512) for the SAME vectors, then the
// two halves merge argmins via LDS. 4 blocks/CU * 8 waves = 32 waves/CU.
__global__ __launch_bounds__(512, 8) void vq_main(const float* __restrict__ z,
                                                  const float* __restrict__ cb,
                                                  const float* __restrict__ esq,
                                                  float* __restrict__ ws,
                                                  float* __restrict__ zq) {
    __shared__ float s_counts[Kc];
    __shared__ float s_sums[Kc * Dc];
    __shared__ float s_mn[512];
    __shared__ int   s_im[512];
    __shared__ float s_loss;

    const int t = threadIdx.x;
    for (int i = t; i < Kc; i += 512) s_counts[i] = 0.f;
    for (int i = t; i < Kc * Dc; i += 512) s_sums[i] = 0.f;
    if (t == 0) s_loss = 0.f;

    const int v = t & 255;                                   // vector slot
    // wave-uniform k-half; readfirstlane so the compiler keeps the codebook
    // index provably uniform -> s_load (scalar) path for cb/esq.
    const int half = __builtin_amdgcn_readfirstlane(t >> 8); // 0 or 1
    const int k0   = half << 8;

    const int m = blockIdx.x * 256 + v;
    const int n = m & (HWc - 1);
    const int b = m >> 12;
    const float* zb = z + b * CHWc + n;

    float zv[Dc], zz[Dc];
#pragma unroll
    for (int c = 0; c < Dc; ++c) {
        zv[c] = zb[c * HWc];              // coalesced across lanes
        zz[c] = -2.0f * zv[c];
    }

    // argmin over this half: score = e_sq[k] - 2*dot(z,e_k)  (monotone-equiv).
    float mn = 3.4e38f;
    int   im = k0;
#pragma unroll 4
    for (int kk = 0; kk < 256; ++kk) {
        const int k = k0 + kk;
        float a = esq[k];                 // uniform -> s_load
#pragma unroll
        for (int c = 0; c < Dc; ++c) {
            const float e = cb[k * Dc + c];   // uniform -> s_load
            a = fmaf(zz[c], e, a);
        }
        const bool cm = a < mn;  // strict <: first index wins ties (ref rule)
        mn = cm ? a : mn;
        im = cm ? k : im;
    }
    s_mn[t] = mn;
    s_im[t] = im;
    __syncthreads();

    if (t < 256) {
        const float mn0 = s_mn[t];
        const float mn1 = s_mn[t + 256];
        const int   im0 = s_im[t];
        const int   im1 = s_im[t + 256];
        // high half wins only on strict < (its indices are larger -> ref rule)
        const int im = (mn1 < mn0) ? im1 : im0;

        // Gather old-codebook row (16 KB table, L1-hot; 32B/lane).
        const float4* cb4 = (const float4*)cb;
        const float4 qa = cb4[im * 2], qb = cb4[im * 2 + 1];
        const float q[Dc] = {qa.x, qa.y, qa.z, qa.w, qb.x, qb.y, qb.z, qb.w};

        float* zqb = zq + b * CHWc + n;
        float lsum = 0.f;
#pragma unroll
        for (int c = 0; c < Dc; ++c) {
            zqb[c * HWc] = q[c];          // coalesced stores
            const float d = q[c] - zv[c];
            lsum = fmaf(d, d, lsum);
        }

        // Per-block LDS histogram (ds_add_f32).
        unsafeAtomicAdd(&s_counts[im], 1.0f);
#pragma unroll
        for (int c = 0; c < Dc; ++c)
            unsafeAtomicAdd(&s_sums[im * Dc + c], zv[c]);
        unsafeAtomicAdd(&s_loss, lsum);
    }
    __syncthreads();

    // Flush non-zero bins to this block's replica accumulator (all 512 thr).
    float* acc = ws + (blockIdx.x & (REP - 1)) * RSTRIDE;
    for (int i = t; i < Kc; i += 512) {
        const float val = s_counts[i];
        if (val != 0.f) unsafeAtomicAdd(&acc[i], val);
    }
    for (int i = t; i < Kc * Dc; i += 512) {
        const float val = s_sums[i];
        if (val != 0.f) unsafeAtomicAdd(&acc[512 + i], val);
    }
    if (t == 0) unsafeAtomicAdd(&acc[4608], s_loss);
}

__global__ __launch_bounds__(512) void vq_final(const float* __restrict__ ws,
                                                const float* __restrict__ ema_cs,
                                                const float* __restrict__ ema_w,
                                                float* __restrict__ out) {
    constexpr float DEC  = 0.99f;
    constexpr float OMD  = (float)(1.0 - 0.99);      // matches jnp f32 cast
    constexpr float EPSf = 1e-5f;
    constexpr float KEPS = (float)(512 * 1e-5);      // 0.00512
    __shared__ float red[512];

    const int k = threadIdx.x;   // 512 threads, 1 block
    float cnt = 0.f;
#pragma unroll
    for (int r = 0; r < REP; ++r) cnt += ws[r * RSTRIDE + k];
    const float ncs = ema_cs[k] * DEC + cnt * OMD;
    red[k] = ncs;
    __syncthreads();
    for (int s = 256; s > 0; s >>= 1) {
        if (k < s) red[k] += red[k + s];
        __syncthreads();
    }
    const float n  = red[0];
    const float cs = (ncs + EPSf) / (n + KEPS) * n;

    float* out_loss = out + TOTALc;          // [1]
    float* out_cb   = out + TOTALc + 1;      // [K*D]
    float* out_cs   = out_cb + Kc * Dc;      // [K]
    float* out_nw   = out_cs + Kc;           // [K*D]

    out_cs[k] = cs;
#pragma unroll
    for (int c = 0; c < Dc; ++c) {
        float sm = 0.f;
#pragma unroll
        for (int r = 0; r < REP; ++r) sm += ws[r * RSTRIDE + 512 + k * Dc + c];
        const float nw = ema_w[k * Dc + c] * DEC + sm * OMD;
        out_nw[k * Dc + c] = nw;
        out_cb[k * Dc + c] = nw / cs;
    }
    if (k == 0) {
        float ls = 0.f;
#pragma unroll
        for (int r = 0; r < REP; ++r) ls += ws[r * RSTRIDE + 4608];
        out_loss[0] = ls * (1.0f / 2097152.0f);  // /2^21 exact
    }
}

extern "C" void kernel_launch(void* const* d_in, const int* in_sizes, int n_in,
                              void* d_out, int out_size, void* d_ws, size_t ws_size,
                              hipStream_t stream) {
    const float* z      = (const float*)d_in[0];
    const float* cb     = (const float*)d_in[1];
    const float* ema_cs = (const float*)d_in[2];
    const float* ema_w  = (const float*)d_in[3];
    float* out = (float*)d_out;
    float* ws  = (float*)d_ws;

    vq_prep<<<32, 256, 0, stream>>>(cb, ws);
    vq_main<<<Mc / 256, 512, 0, stream>>>(z, cb, ws + ACC_FLOATS, ws, out);
    vq_final<<<1, 512, 0, stream>>>(ws, ema_cs, ema_w, out);
}

// Round 4
// 112.371 us; speedup vs baseline: 1.3100x; 1.1503x over previous
//
#include <hip/hip_runtime.h>

// VQ-VAE forward + EMA update, MI355X.
// Sizes fixed by the reference: B=64, C=D=8, H=W=64, K=512.
constexpr int Kc   = 512;
constexpr int Dc   = 8;
constexpr int HWc  = 4096;            // 64*64
constexpr int CHWc = Dc * HWc;        // 32768
constexpr int Mc   = 64 * HWc;        // 262144 vectors
constexpr int TOTALc = Mc * Dc;       // 2097152 elements of z / z_q

// 8 replica accumulators (one per XCD via blockIdx&7) to cut atomic contention.
constexpr int REP      = 8;
constexpr int RSTRIDE  = 4616;        // 512 counts + 4096 sums + 1 loss + 7 pad
constexpr int ACC_FLOATS = REP * RSTRIDE;   // 36928 floats (~148 KB)
// d_ws float layout:
//   [0 .. ACC_FLOATS)            replica accumulators (counts | sums | loss | pad) x8
//   [ACC_FLOATS .. +512)         e_sq[k]

__global__ __launch_bounds__(256) void vq_prep(const float* __restrict__ cb,
                                               float* __restrict__ ws) {
    const int tid = blockIdx.x * 256 + threadIdx.x;
    float4* w4 = (float4*)ws;
    for (int i = tid; i < ACC_FLOATS / 4; i += gridDim.x * 256)
        w4[i] = float4{0.f, 0.f, 0.f, 0.f};
    if (blockIdx.x == 0) {
        for (int k = threadIdx.x; k < Kc; k += 256) {
            float s = 0.f;
#pragma unroll
            for (int c = 0; c < Dc; ++c) {
                const float e = cb[k * Dc + c];
                s = fmaf(e, e, s);
            }
            ws[ACC_FLOATS + k] = s;
        }
    }
}

// 1024 blocks x 512 threads; block owns 256 consecutive vectors.
// k-group g = t>>7 (2 waves) scans codes [g*128, g*128+128) for all 256
// vectors; each thread scores V=2 vectors (vl and vl+128) per codebook read,
// halving the scalar-fetch stream per unit work. 4 blocks/CU = 32 waves/CU.
__global__ __launch_bounds__(512, 8) void vq_main(const float* __restrict__ z,
                                                  const float* __restrict__ cb,
                                                  const float* __restrict__ esq,
                                                  float* __restrict__ ws,
                                                  float* __restrict__ zq) {
    __shared__ float s_counts[Kc];
    __shared__ float s_sums[Kc * Dc];
    __shared__ float s_mn[4][256];
    __shared__ int   s_im[4][256];
    __shared__ float s_loss;

    const int t = threadIdx.x;
    for (int i = t; i < Kc; i += 512) s_counts[i] = 0.f;
    for (int i = t; i < Kc * Dc; i += 512) s_sums[i] = 0.f;
    if (t == 0) s_loss = 0.f;

    const int vl = t & 127;
    // wave-uniform k-group; readfirstlane keeps the codebook index provably
    // uniform -> s_load (scalar) path for cb/esq.
    const int g  = __builtin_amdgcn_readfirstlane(t >> 7);   // 0..3
    const int k0 = g << 7;

    const int base = blockIdx.x * 256;        // 256-aligned -> one batch idx
    const int n0 = (base + vl) & (HWc - 1);
    const int b  = base >> 12;
    const float* zb = z + b * CHWc + n0;

    float zz0[Dc], zz1[Dc];
#pragma unroll
    for (int c = 0; c < Dc; ++c) {
        zz0[c] = -2.0f * zb[c * HWc];         // coalesced across lanes
        zz1[c] = -2.0f * zb[c * HWc + 128];
    }

    // argmin over this k-group: score = e_sq[k] - 2*dot(z,e_k) (monotone-eq).
    float mn0 = 3.4e38f, mn1 = 3.4e38f;
    int   i0 = k0, i1 = k0;
#pragma unroll 4
    for (int kk = 0; kk < 128; ++kk) {
        const int k = k0 + kk;
        float a0 = esq[k];                    // uniform -> s_load
        float a1 = a0;
#pragma unroll
        for (int c = 0; c < Dc; ++c) {
            const float e = cb[k * Dc + c];   // uniform -> s_load
            a0 = fmaf(zz0[c], e, a0);
            a1 = fmaf(zz1[c], e, a1);
        }
        const bool c0 = a0 < mn0;  // strict <: first index wins ties (ref)
        mn0 = c0 ? a0 : mn0;
        i0  = c0 ? k  : i0;
        const bool c1 = a1 < mn1;
        mn1 = c1 ? a1 : mn1;
        i1  = c1 ? k  : i1;
    }
    s_mn[g][vl]       = mn0;
    s_im[g][vl]       = i0;
    s_mn[g][vl + 128] = mn1;
    s_im[g][vl + 128] = i1;
    __syncthreads();

    if (t < 256) {
        const int v = t;                      // block-local vector id
        float mn = s_mn[0][v];
        int   im = s_im[0][v];
#pragma unroll
        for (int gg = 1; gg < 4; ++gg) {
            const float m2 = s_mn[gg][v];     // groups ascending in k:
            const int   j2 = s_im[gg][v];     // strict < keeps first index
            const bool  c2 = m2 < mn;
            mn = c2 ? m2 : mn;
            im = c2 ? j2 : im;
        }

        // Gather old-codebook row (16 KB table, L1-hot; 32B/lane).
        const float4* cb4 = (const float4*)cb;
        const float4 qa = cb4[im * 2], qb = cb4[im * 2 + 1];
        const float q[Dc] = {qa.x, qa.y, qa.z, qa.w, qb.x, qb.y, qb.z, qb.w};

        const int nv = (base + v) & (HWc - 1);
        const float* zv = z + b * CHWc + nv;  // re-read z (L1/L2-hot)
        float* zqv = zq + b * CHWc + nv;
        float lsum = 0.f;
        float zr[Dc];
#pragma unroll
        for (int c = 0; c < Dc; ++c) {
            zr[c] = zv[c * HWc];
            zqv[c * HWc] = q[c];              // coalesced stores
            const float d = q[c] - zr[c];
            lsum = fmaf(d, d, lsum);
        }

        // Per-block LDS histogram (ds_add_f32).
        unsafeAtomicAdd(&s_counts[im], 1.0f);
#pragma unroll
        for (int c = 0; c < Dc; ++c)
            unsafeAtomicAdd(&s_sums[im * Dc + c], zr[c]);
        unsafeAtomicAdd(&s_loss, lsum);
    }
    __syncthreads();

    // Flush non-zero bins to this block's replica accumulator (all 512 thr).
    float* acc = ws + (blockIdx.x & (REP - 1)) * RSTRIDE;
    for (int i = t; i < Kc; i += 512) {
        const float val = s_counts[i];
        if (val != 0.f) unsafeAtomicAdd(&acc[i], val);
    }
    for (int i = t; i < Kc * Dc; i += 512) {
        const float val = s_sums[i];
        if (val != 0.f) unsafeAtomicAdd(&acc[512 + i], val);
    }
    if (t == 0) unsafeAtomicAdd(&acc[4608], s_loss);
}

__global__ __launch_bounds__(512) void vq_final(const float* __restrict__ ws,
                                                const float* __restrict__ ema_cs,
                                                const float* __restrict__ ema_w,
                                                float* __restrict__ out) {
    constexpr float DEC  = 0.99f;
    constexpr float OMD  = (float)(1.0 - 0.99);      // matches jnp f32 cast
    constexpr float EPSf = 1e-5f;
    constexpr float KEPS = (float)(512 * 1e-5);      // 0.00512
    __shared__ float red[512];
    __shared__ float s_cs[512];

    const int t = threadIdx.x;   // 512 threads, 1 block
    // counts: lane-consecutive reads per replica (coalesced)
    float cnt = 0.f;
#pragma unroll
    for (int r = 0; r < REP; ++r) cnt += ws[r * RSTRIDE + t];
    const float ncs = ema_cs[t] * DEC + cnt * OMD;
    red[t] = ncs;
    __syncthreads();
    for (int s = 256; s > 0; s >>= 1) {
        if (t < s) red[t] += red[t + s];
        __syncthreads();
    }
    const float n  = red[0];
    const float cs = (ncs + EPSf) / (n + KEPS) * n;
    s_cs[t] = cs;

    float* out_loss = out + TOTALc;          // [1]
    float* out_cb   = out + TOTALc + 1;      // [K*D]
    float* out_cs   = out_cb + Kc * Dc;      // [K]
    float* out_nw   = out_cs + Kc;           // [K*D]

    out_cs[t] = cs;
    __syncthreads();

    // sums: fully coalesced element-major passes
    for (int e = t; e < Kc * Dc; e += 512) {
        float sm = 0.f;
#pragma unroll
        for (int r = 0; r < REP; ++r) sm += ws[r * RSTRIDE + 512 + e];
        const float nw = ema_w[e] * DEC + sm * OMD;
        out_nw[e] = nw;
        out_cb[e] = nw / s_cs[e >> 3];
    }
    if (t == 0) {
        float ls = 0.f;
#pragma unroll
        for (int r = 0; r < REP; ++r) ls += ws[r * RSTRIDE + 4608];
        out_loss[0] = ls * (1.0f / 2097152.0f);  // /2^21 exact
    }
}

extern "C" void kernel_launch(void* const* d_in, const int* in_sizes, int n_in,
                              void* d_out, int out_size, void* d_ws, size_t ws_size,
                              hipStream_t stream) {
    const float* z      = (const float*)d_in[0];
    const float* cb     = (const float*)d_in[1];
    const float* ema_cs = (const float*)d_in[2];
    const float* ema_w  = (const float*)d_in[3];
    float* out = (float*)d_out;
    float* ws  = (float*)d_ws;

    vq_prep<<<32, 256, 0, stream>>>(cb, ws);
    vq_main<<<Mc / 256, 512, 0, stream>>>(z, cb, ws + ACC_FLOATS, ws, out);
    vq_final<<<1, 512, 0, stream>>>(ws, ema_cs, ema_w, out);
}